// Round 3
// baseline (183.671 us; speedup 1.0000x reference)
//
#include <hip/hip_runtime.h>

// SSIM loss, fused single-pass.
// Layout: (16,3,512,512) f32, planes = 48, H=W=512.
// Box filter = separable 11-tap uniform mean with zero padding.
// Strategy: per block = (plane, x-tile TW=128, y-strip SH=128).
//   H phase: horizontal sliding-window sums of 5 quantities -> LDS row ring.
//   V phase: vertical running sums over ring rows + SSIM + reduce.

#define TW    128   // tile width (output columns per block)
#define SH    128   // strip height (output rows per block)
#define CAP   28    // LDS ring capacity in rows; >= batch(16) + window(11) + 1
#define ROWF  132   // floats per ring row: 128 + swizzle pad
#define NQ    5

#define C1V   (0.01f * 0.01f)
#define C2V   (0.03f * 0.03f)

__device__ __forceinline__ int swz(int x) { return x + (x >> 5); }

__launch_bounds__(256, 2)
__global__ void ssim_fused(const float* __restrict__ img1,
                           const float* __restrict__ img2,
                           float* __restrict__ out)
{
    __shared__ float ring[CAP * NQ * ROWF];

    const int xt    = blockIdx.x;   // 0..3
    const int yt    = blockIdx.y;   // 0..3
    const int plane = blockIdx.z;   // 0..47
    const int x0 = xt * TW;
    const int y0 = yt * SH;
    const size_t pbase = (size_t)plane * 512 * 512;

    const int tid = threadIdx.x;
    const int hj  = tid >> 4;   // H: row within batch (0..15)
    const int hk  = tid & 15;   // H: run index (0..15), K=8 columns each
    const int vx  = tid;        // V: column (active if < TW)

    const int xl = x0 + hk * 8 - 8;   // f4-aligned load start (may be OOB)

    float vs0 = 0.f, vs1 = 0.f, vs2 = 0.f, vs3 = 0.f, vs4 = 0.f;
    float accs = 0.f;

    for (int m = 0; m < 9; ++m) {
        // ---------------- H phase: rows rel [16m, 16m+16) ----------------
        {
            const int rel = 16 * m + hj;
            const int r   = y0 - 5 + rel;         // absolute image row
            float a[24], b[24];
            if (r >= 0 && r < 512) {
                const float* p1 = img1 + pbase + (size_t)r * 512;
                const float* p2 = img2 + pbase + (size_t)r * 512;
#pragma unroll
                for (int u = 0; u < 6; ++u) {
                    const int c4 = xl + 4 * u;
                    float4 v1, v2;
                    if (c4 >= 0 && c4 < 512) {
                        v1 = *(const float4*)(p1 + c4);
                        v2 = *(const float4*)(p2 + c4);
                    } else {
                        v1 = float4{0.f, 0.f, 0.f, 0.f};
                        v2 = float4{0.f, 0.f, 0.f, 0.f};
                    }
                    a[4*u+0] = v1.x; a[4*u+1] = v1.y; a[4*u+2] = v1.z; a[4*u+3] = v1.w;
                    b[4*u+0] = v2.x; b[4*u+1] = v2.y; b[4*u+2] = v2.z; b[4*u+3] = v2.w;
                }
            } else {
#pragma unroll
                for (int u = 0; u < 24; ++u) { a[u] = 0.f; b[u] = 0.f; }
            }

            const int slot = rel % CAP;                 // uniform scalar
            float* rb = &ring[(slot * NQ) * ROWF];

            // window for output i covers p[i..i+10]; p[c] = product at loaded col c+3
#define EMIT_Q(QI, PEXPR)                                                   \
            {                                                               \
                float p[18];                                                \
                _Pragma("unroll")                                           \
                for (int c = 0; c < 18; ++c) {                              \
                    const float av = a[c + 3];                              \
                    const float bv = b[c + 3];                              \
                    (void)av; (void)bv;                                     \
                    p[c] = (PEXPR);                                         \
                }                                                           \
                float w = p[0]+p[1]+p[2]+p[3]+p[4]+p[5]+p[6]+p[7]+p[8]+p[9]+p[10]; \
                float* qb = rb + (QI) * ROWF;                               \
                qb[swz(hk * 8 + 0)] = w;                                    \
                _Pragma("unroll")                                           \
                for (int i = 1; i < 8; ++i) {                               \
                    w += p[10 + i] - p[i - 1];                              \
                    qb[swz(hk * 8 + i)] = w;                                \
                }                                                           \
            }

            EMIT_Q(0, av)
            EMIT_Q(1, bv)
            EMIT_Q(2, av * av)
            EMIT_Q(3, bv * bv)
            EMIT_Q(4, av * bv)
#undef EMIT_Q
        }
        __syncthreads();

        // ---------------- V phase: consume rows, emit SSIM ----------------
        if (vx < TW) {
            const int xs = swz(vx);
#pragma unroll
            for (int jj = 0; jj < 16; ++jj) {
                const int rel = 16 * m + jj;     // index of row (y+5)
                const int aslot = rel % CAP;
                const float* ab = &ring[(aslot * NQ) * ROWF];
                vs0 += ab[0 * ROWF + xs];
                vs1 += ab[1 * ROWF + xs];
                vs2 += ab[2 * ROWF + xs];
                vs3 += ab[3 * ROWF + xs];
                vs4 += ab[4 * ROWF + xs];
                if (rel >= 11) {
                    const int sslot = (rel - 11) % CAP;
                    const float* sb = &ring[(sslot * NQ) * ROWF];
                    vs0 -= sb[0 * ROWF + xs];
                    vs1 -= sb[1 * ROWF + xs];
                    vs2 -= sb[2 * ROWF + xs];
                    vs3 -= sb[3 * ROWF + xs];
                    vs4 -= sb[4 * ROWF + xs];
                }
                if (rel >= 10 && rel <= 137) {   // y = y0 + rel - 10 in [y0, y0+128)
                    const float s = 1.0f / 121.0f;
                    const float mu1 = vs0 * s, mu2 = vs1 * s;
                    const float e11 = vs2 * s, e22 = vs3 * s, e12 = vs4 * s;
                    const float mu1s = mu1 * mu1;
                    const float mu2s = mu2 * mu2;
                    const float m12  = mu1 * mu2;
                    const float s1  = e11 - mu1s;
                    const float s2  = e22 - mu2s;
                    const float s12 = e12 - m12;
                    const float num = (2.f * m12 + C1V) * (2.f * s12 + C2V);
                    const float den = (mu1s + mu2s + C1V) * (s1 + s2 + C2V);
                    accs += num * __builtin_amdgcn_rcpf(den);
                }
            }
        }
        __syncthreads();
    }

    // ---------------- reduction ----------------
    float tot = accs;
#pragma unroll
    for (int off = 32; off > 0; off >>= 1)
        tot += __shfl_down(tot, off);
    if ((tid & 63) == 0) ring[tid >> 6] = tot;
    __syncthreads();
    if (tid == 0) {
        const float t = ring[0] + ring[1] + ring[2] + ring[3];
        // out = sum over blocks of (1/768 - partial/N) = 1 - mean(ssim)
        atomicAdd(out, 1.0f / 768.0f - t * (1.0f / 12582912.0f));
    }
}

extern "C" void kernel_launch(void* const* d_in, const int* in_sizes, int n_in,
                              void* d_out, int out_size, void* d_ws, size_t ws_size,
                              hipStream_t stream)
{
    const float* img1 = (const float*)d_in[0];
    const float* img2 = (const float*)d_in[1];
    float* out = (float*)d_out;

    hipMemsetAsync(out, 0, sizeof(float), stream);

    dim3 grid(4, 4, 48);
    ssim_fused<<<grid, dim3(256), 0, stream>>>(img1, img2, out);
}

// Round 5
// 144.133 us; speedup vs baseline: 1.2743x; 1.2743x over previous
//
#include <hip/hip_runtime.h>
#include <hip/hip_fp16.h>

// SSIM loss, fused, producer/consumer pipelined.
// (16,3,512,512) f32 -> scalar. Box = separable 11-tap mean, zero pad.
// Block = (plane, 128x128 tile), 256 threads:
//   tid 0..127  : H producers — 8 rows/iter, runs of 8 cols, h-sums -> fp16 ring
//   tid 128..255: V consumers — 1 col each, running vertical sums + SSIM
// Ring: CAP=28 row-slots x 3 dword planes (q0q1, q2q3, q4) x 132 cols (swizzled).
// 44.4 KB LDS -> 3 blocks/CU; grid 768 = 3 x 256 CUs exactly.

#define CAP   28
#define ROWF  132
#define SSTR  (3 * ROWF)
#define C1K   1.4641f      // 0.01^2 * 121^2
#define C2K   13.1769f     // 0.03^2 * 121^2

__device__ __forceinline__ int swz(int x) { return x + (x >> 5); }

__launch_bounds__(256, 3)
__global__ void ssim_fused(const float* __restrict__ img1,
                           const float* __restrict__ img2,
                           float* __restrict__ out)
{
    __shared__ unsigned int ring[CAP * SSTR];

    const int x0 = blockIdx.x * 128;
    const int y0 = blockIdx.y * 128;
    const size_t pbase = (size_t)blockIdx.z * (512 * 512);
    const int tid = threadIdx.x;

    const int hj = tid >> 4;            // producer: row in batch (0..7)
    const int hk = tid & 15;            // producer: run index (8 cols)
    const int xl = x0 + hk * 8 - 8;     // f4-aligned load start
    const int xs = swz(tid & 127);      // consumer: swizzled col

    float S0 = 0.f, S1 = 0.f, S2 = 0.f, S3 = 0.f, S4 = 0.f, accs = 0.f;
    int pslot = hj;                     // producer slot = (8t+hj) % CAP, maintained
    int cbase = 0;                      // consumer slot of rel = 8*(t-1)

    for (int t = 0; t < 19; ++t) {
        if (tid < 128) {
            // ---------------- producer: batch t (rels 8t..8t+7) ----------------
            if (t < 18) {
                const int rel = 8 * t + hj;
                const int r   = y0 - 5 + rel;
                float a[24], b[24];
                if ((unsigned)r < 512u) {
                    const float* p1 = img1 + pbase + (size_t)r * 512;
                    const float* p2 = img2 + pbase + (size_t)r * 512;
#pragma unroll
                    for (int u = 0; u < 6; ++u) {
                        const int c4 = xl + 4 * u;
                        float4 v1 = {0.f, 0.f, 0.f, 0.f};
                        float4 v2 = {0.f, 0.f, 0.f, 0.f};
                        if ((unsigned)c4 < 512u) {
                            v1 = *(const float4*)(p1 + c4);
                            v2 = *(const float4*)(p2 + c4);
                        }
                        a[4*u] = v1.x; a[4*u+1] = v1.y; a[4*u+2] = v1.z; a[4*u+3] = v1.w;
                        b[4*u] = v2.x; b[4*u+1] = v2.y; b[4*u+2] = v2.z; b[4*u+3] = v2.w;
                    }
                } else {
#pragma unroll
                    for (int u = 0; u < 24; ++u) { a[u] = 0.f; b[u] = 0.f; }
                }

                // initial 11-window sums: window of output col hk*8 covers a[3..13]
                float w0 = 0.f, w1 = 0.f, w2 = 0.f, w3 = 0.f, w4 = 0.f;
#pragma unroll
                for (int c = 0; c < 11; ++c) {
                    const float av = a[c + 3], bv = b[c + 3];
                    w0 += av; w1 += bv; w2 += av * av; w3 += bv * bv; w4 += av * bv;
                }

                unsigned int* rb = &ring[pslot * SSTR];
#pragma unroll
                for (int i = 0; i < 8; ++i) {
                    const int ad = swz(hk * 8 + i);
                    const __half2 h01 = __floats2half2_rn(w0, w1);
                    const __half2 h23 = __floats2half2_rn(w2, w3);
                    const __half2 h4x = __floats2half2_rn(w4, 0.f);
                    rb[ad]            = *(const unsigned int*)&h01;
                    rb[ad + ROWF]     = *(const unsigned int*)&h23;
                    rb[ad + 2 * ROWF] = *(const unsigned int*)&h4x;
                    if (i < 7) {   // slide: add a[14+i], drop a[3+i]
                        const float aN = a[14 + i], aO = a[3 + i];
                        const float bN = b[14 + i], bO = b[3 + i];
                        w0 += aN - aO;
                        w1 += bN - bO;
                        w2 += aN * aN - aO * aO;
                        w3 += bN * bN - bO * bO;
                        w4 += aN * bN - aO * bO;
                    }
                }
                pslot += 8; if (pslot >= CAP) pslot -= CAP;
            }
        } else {
            // ---------------- consumer: batch t-1 (rels 8(t-1)..8(t-1)+7) ------
            if (t >= 1) {
#pragma unroll
                for (int jj = 0; jj < 8; ++jj) {
                    const int rel = 8 * (t - 1) + jj;
                    int sa = cbase + jj; if (sa >= CAP) sa -= CAP;
                    const unsigned int* ab = &ring[sa * SSTR + xs];
                    const unsigned int u01 = ab[0], u23 = ab[ROWF], u4 = ab[2 * ROWF];
                    const float2 f01 = __half22float2(*(const __half2*)&u01);
                    const float2 f23 = __half22float2(*(const __half2*)&u23);
                    const float2 f4v = __half22float2(*(const __half2*)&u4);
                    S0 += f01.x; S1 += f01.y; S2 += f23.x; S3 += f23.y; S4 += f4v.x;
                    if (rel >= 11) {
                        int ss = sa - 11; if (ss < 0) ss += CAP;
                        const unsigned int* sb = &ring[ss * SSTR + xs];
                        const unsigned int v01 = sb[0], v23 = sb[ROWF], v4 = sb[2 * ROWF];
                        const float2 g01 = __half22float2(*(const __half2*)&v01);
                        const float2 g23 = __half22float2(*(const __half2*)&v23);
                        const float2 g4v = __half22float2(*(const __half2*)&v4);
                        S0 -= g01.x; S1 -= g01.y; S2 -= g23.x; S3 -= g23.y; S4 -= g4v.x;
                    }
                    if (rel >= 10 && rel <= 137) {
                        // SSIM on raw sums: the 121^4 factor cancels in num/den.
                        const float t01 = S0 * S1;
                        const float p0  = S0 * S0, p1 = S1 * S1;
                        const float num = (2.f * t01 + C1K)
                                        * (2.f * (121.f * S4 - t01) + C2K);
                        const float den = (p0 + p1 + C1K)
                                        * (121.f * (S2 + S3) - p0 - p1 + C2K);
                        accs += num * __builtin_amdgcn_rcpf(den);
                    }
                }
                cbase += 8; if (cbase >= CAP) cbase -= CAP;
            }
        }
        __syncthreads();
    }

    // ---------------- block reduction + global atomic ----------------
    float tot = accs;
#pragma unroll
    for (int off = 32; off > 0; off >>= 1)
        tot += __shfl_down(tot, off);
    float* red = (float*)ring;
    if ((tid & 63) == 0) red[tid >> 6] = tot;
    __syncthreads();
    if (tid == 0) {
        const float s = red[0] + red[1] + red[2] + red[3];
        atomicAdd(out, 1.0f / 768.0f - s * (1.0f / 12582912.0f));
    }
}

extern "C" void kernel_launch(void* const* d_in, const int* in_sizes, int n_in,
                              void* d_out, int out_size, void* d_ws, size_t ws_size,
                              hipStream_t stream)
{
    const float* img1 = (const float*)d_in[0];
    const float* img2 = (const float*)d_in[1];
    float* out = (float*)d_out;

    hipMemsetAsync(out, 0, sizeof(float), stream);

    dim3 grid(4, 4, 48);
    ssim_fused<<<grid, dim3(256), 0, stream>>>(img1, img2, out);
}